// Round 1
// baseline (448.941 us; speedup 1.0000x reference)
//
#include <hip/hip_runtime.h>

typedef __attribute__((ext_vector_type(8))) short short8v;
typedef __attribute__((ext_vector_type(4))) float float4v;
typedef __attribute__((ext_vector_type(2))) unsigned int u32x2;
typedef __attribute__((ext_vector_type(4))) unsigned int u32x4;
typedef unsigned short u16;
typedef unsigned int u32;

#define NN 4096
#define EE 32768
#define DI 128
#define DO 128

__device__ __forceinline__ u16 f2bf(float f) {
    u32 u = __builtin_bit_cast(u32, f);
    u32 r = u + 0x7fffu + ((u >> 16) & 1u);   // round-to-nearest-even
    return (u16)(r >> 16);
}
__device__ __forceinline__ u32 pack2bf(float lo, float hi) {
    return (u32)f2bf(lo) | ((u32)f2bf(hi) << 16);
}

// ---------- staging helpers (256 threads/block) ----------

// f32 tile [R rows x C cols] (row stride ld floats) -> LDS bf16 [R][C], XOR-swizzled
template<int R, int C>
__device__ __forceinline__ void stage_f32_bf16(char* lds, const float* src, int ld) {
    constexpr int CH = C / 8;
    constexpr int ITER = (R * CH) / 256;
#pragma unroll
    for (int it = 0; it < ITER; ++it) {
        int c = it * 256 + (int)threadIdx.x;
        int row = c / CH, col8 = c % CH;
        const float* p = src + (size_t)row * ld + col8 * 8;
        float4v v0 = *(const float4v*)p;
        float4v v1 = *(const float4v*)(p + 4);
        u32x4 w;
        w[0] = pack2bf(v0[0], v0[1]);
        w[1] = pack2bf(v0[2], v0[3]);
        w[2] = pack2bf(v1[0], v1[1]);
        w[3] = pack2bf(v1[2], v1[3]);
        int kb = col8 * 16;
        *(u32x4*)(lds + row * (C * 2) + (kb ^ ((row & 7) << 4))) = w;
    }
}

// bf16 tile [R][C] (row stride ld elems) -> LDS bf16 [R][C], XOR-swizzled
template<int R, int C>
__device__ __forceinline__ void stage_bf16cp(char* lds, const u16* src, int ld) {
    constexpr int CH = C / 8;
    constexpr int ITER = (R * CH) / 256;
#pragma unroll
    for (int it = 0; it < ITER; ++it) {
        int c = it * 256 + (int)threadIdx.x;
        int row = c / CH, col8 = c % CH;
        u32x4 v = *(const u32x4*)(src + (size_t)row * ld + col8 * 8);
        int kb = col8 * 16;
        *(u32x4*)(lds + row * (C * 2) + (kb ^ ((row & 7) << 4))) = v;
    }
}

// f32 [64 n rows][cols] at (n0, eb) of big [NN][EE] matrix -> LDS bf16 [64 e][64 n] (transposed)
__device__ __forceinline__ void stage_T64(char* lds, const float* src, int n0, int eb) {
    int t = (int)threadIdx.x;
    int eq = t & 15, nq = t >> 4;   // 16 e-quads x 16 n-quads
    const float* p = src + (size_t)(n0 + nq * 4) * EE + eb + eq * 4;
    float4v r0 = *(const float4v*)p;
    float4v r1 = *(const float4v*)(p + EE);
    float4v r2 = *(const float4v*)(p + 2 * EE);
    float4v r3 = *(const float4v*)(p + 3 * EE);
#pragma unroll
    for (int j = 0; j < 4; ++j) {
        int e = eq * 4 + j;
        u32x2 w;
        w[0] = pack2bf(r0[j], r1[j]);
        w[1] = pack2bf(r2[j], r3[j]);
        *(u32x2*)(lds + e * 128 + ((nq * 8) ^ ((e & 7) << 4))) = w;
    }
}

// read one 16x32 MFMA operand fragment (A or B) from swizzled LDS tile
template<int ROWB>
__device__ __forceinline__ short8v ldfrag(const char* base, int row16, int kk) {
    int l = (int)threadIdx.x & 63;
    int row = row16 + (l & 15);
    int kb = kk * 64 + ((l >> 4) << 4);
    return *(const short8v*)(base + row * ROWB + (kb ^ ((row & 7) << 4)));
}

// ---------- kernel 1: ATB[mo][n] = sum_i f_w[o][m*128+i] * x[n][i]  (mo = m*128+o) ----------
__global__ __launch_bounds__(256) void k1_ab(const float* __restrict__ x,
                                             const float* __restrict__ fw,
                                             u16* __restrict__ ATB) {
    __shared__ __align__(16) char lds[64 * 1024];
    char* aL = lds;              // [128 mo][128 i], ROWB 256
    char* bL = lds + 32 * 1024;  // [128 n][128 i]
    int mb = (int)blockIdx.x >> 5, nb = (int)blockIdx.x & 31;
    stage_f32_bf16<128, 128>(aL, fw + mb * 128, 2 * DI);
    stage_f32_bf16<128, 128>(bL, x + (size_t)nb * 128 * DI, DI);
    __syncthreads();
    int w = (int)threadIdx.x >> 6, l = (int)threadIdx.x & 63;
    int wr = w >> 1, wc = w & 1;
    float4v acc[4][4] = {};
#pragma unroll
    for (int kk = 0; kk < 4; ++kk) {
        short8v af[4], bf[4];
#pragma unroll
        for (int m = 0; m < 4; ++m) af[m] = ldfrag<256>(aL, wr * 64 + m * 16, kk);
#pragma unroll
        for (int n2 = 0; n2 < 4; ++n2) bf[n2] = ldfrag<256>(bL, wc * 64 + n2 * 16, kk);
#pragma unroll
        for (int m = 0; m < 4; ++m)
#pragma unroll
            for (int n2 = 0; n2 < 4; ++n2)
                acc[m][n2] = __builtin_amdgcn_mfma_f32_16x16x32_bf16(af[m], bf[n2], acc[m][n2], 0, 0, 0);
    }
#pragma unroll
    for (int m = 0; m < 4; ++m)
#pragma unroll
        for (int n2 = 0; n2 < 4; ++n2)
#pragma unroll
            for (int r = 0; r < 4; ++r) {
                int mo = mb * 128 + wr * 64 + m * 16 + ((l >> 4) << 2) + r;
                int n  = nb * 128 + wc * 64 + n2 * 16 + (l & 15);
                ATB[(size_t)mo * NN + n] = f2bf(acc[m][n2][r]);
            }
}

// ---------- kernel 2: YT[o][e] = relu(sum_n ATB[0][o][n]*src[n][e] + ATB[1][o][n]*tgt[n][e] + fb[o]) ----------
__global__ __launch_bounds__(256) void k2_y(const float* __restrict__ src,
                                            const float* __restrict__ tgt,
                                            const u16* __restrict__ ATB,
                                            const float* __restrict__ fb,
                                            u16* __restrict__ YT) {
    __shared__ __align__(16) char lds[48 * 1024];
    char* atbL = lds;             // [256 mo][64 k] bf16, ROWB 128
    char* stL  = lds + 32 * 1024; // 2 x [64 e][64 n] bf16
    int eb = (int)blockIdx.x * 64;
    int w = (int)threadIdx.x >> 6, l = (int)threadIdx.x & 63;
    float4v acc[2][4] = {};
    for (int k0 = 0; k0 < NN; k0 += 64) {
        __syncthreads();
        stage_bf16cp<256, 64>(atbL, ATB + k0, NN);
        stage_T64(stL, src, k0, eb);
        stage_T64(stL + 8 * 1024, tgt, k0, eb);
        __syncthreads();
#pragma unroll
        for (int mat = 0; mat < 2; ++mat) {
            const char* aL = atbL + mat * 16 * 1024;
            const char* bL = stL + mat * 8 * 1024;
#pragma unroll
            for (int kk = 0; kk < 2; ++kk) {
                short8v a0 = ldfrag<128>(aL, w * 32, kk);
                short8v a1 = ldfrag<128>(aL, w * 32 + 16, kk);
#pragma unroll
                for (int n2 = 0; n2 < 4; ++n2) {
                    short8v b = ldfrag<128>(bL, n2 * 16, kk);
                    acc[0][n2] = __builtin_amdgcn_mfma_f32_16x16x32_bf16(a0, b, acc[0][n2], 0, 0, 0);
                    acc[1][n2] = __builtin_amdgcn_mfma_f32_16x16x32_bf16(a1, b, acc[1][n2], 0, 0, 0);
                }
            }
        }
    }
#pragma unroll
    for (int m = 0; m < 2; ++m)
#pragma unroll
        for (int n2 = 0; n2 < 4; ++n2)
#pragma unroll
            for (int r = 0; r < 4; ++r) {
                int o = w * 32 + m * 16 + ((l >> 4) << 2) + r;
                int e = eb + n2 * 16 + (l & 15);
                float v = acc[m][n2][r] + fb[o];
                v = v > 0.f ? v : 0.f;
                YT[(size_t)o * EE + e] = f2bf(v);
            }
}

// ---------- kernel 3: part[kc][n][o] = sum_{e in chunk kc} tgt[n][e] * YT[o][e] ----------
__global__ __launch_bounds__(256) void k3_part(const float* __restrict__ tgt,
                                               const u16* __restrict__ YT,
                                               float* __restrict__ part) {
    __shared__ __align__(16) char lds[24 * 1024];
    char* tL = lds;              // [64 n][64 e]
    char* yL = lds + 8 * 1024;   // [128 o][64 e]
    int mb = (int)blockIdx.x & 63, kc = (int)blockIdx.x >> 6;
    int e0 = kc * 4096;
    int w = (int)threadIdx.x >> 6, l = (int)threadIdx.x & 63;
    int wr = w >> 1, wc = w & 1;
    float4v acc[2][4] = {};
    for (int k0 = 0; k0 < 4096; k0 += 64) {
        __syncthreads();
        stage_f32_bf16<64, 64>(tL, tgt + (size_t)mb * 64 * EE + e0 + k0, EE);
        stage_bf16cp<128, 64>(yL, YT + e0 + k0, EE);
        __syncthreads();
#pragma unroll
        for (int kk = 0; kk < 2; ++kk) {
            short8v a0 = ldfrag<128>(tL, wr * 32, kk);
            short8v a1 = ldfrag<128>(tL, wr * 32 + 16, kk);
#pragma unroll
            for (int n2 = 0; n2 < 4; ++n2) {
                short8v b = ldfrag<128>(yL, wc * 64 + n2 * 16, kk);
                acc[0][n2] = __builtin_amdgcn_mfma_f32_16x16x32_bf16(a0, b, acc[0][n2], 0, 0, 0);
                acc[1][n2] = __builtin_amdgcn_mfma_f32_16x16x32_bf16(a1, b, acc[1][n2], 0, 0, 0);
            }
        }
    }
#pragma unroll
    for (int m = 0; m < 2; ++m)
#pragma unroll
        for (int n2 = 0; n2 < 4; ++n2)
#pragma unroll
            for (int r = 0; r < 4; ++r) {
                int n = mb * 64 + wr * 32 + m * 16 + ((l >> 4) << 2) + r;
                int o = wc * 64 + n2 * 16 + (l & 15);
                part[((size_t)kc * NN + n) * DO + o] = acc[m][n2][r];
            }
}

// ---------- kernel 4: out = sum_kc part[kc] ----------
__global__ __launch_bounds__(256) void k4_red(const float* __restrict__ part,
                                              float* __restrict__ out) {
    size_t i = ((size_t)blockIdx.x * 256 + threadIdx.x) * 4;
    float4v s = {0.f, 0.f, 0.f, 0.f};
#pragma unroll
    for (int kc = 0; kc < 8; ++kc)
        s += *(const float4v*)(part + (size_t)kc * NN * DO + i);
    *(float4v*)(out + i) = s;
}

extern "C" void kernel_launch(void* const* d_in, const int* in_sizes, int n_in,
                              void* d_out, int out_size, void* d_ws, size_t ws_size,
                              hipStream_t stream) {
    const float* x   = (const float*)d_in[0];
    const float* src = (const float*)d_in[1];
    const float* tgt = (const float*)d_in[2];
    const float* fw  = (const float*)d_in[3];
    const float* fb  = (const float*)d_in[4];
    float* out = (float*)d_out;

    char* ws = (char*)d_ws;
    u16*   ATB  = (u16*)ws;                                    //  2 MB: [256][4096] bf16
    u16*   YT   = (u16*)(ws + (size_t)2 * 1024 * 1024);        //  8 MB: [128][32768] bf16
    float* PART = (float*)(ws + (size_t)10 * 1024 * 1024);     // 16 MB: [8][4096][128] f32

    k1_ab <<<64,  256, 0, stream>>>(x, fw, ATB);
    k2_y  <<<512, 256, 0, stream>>>(src, tgt, ATB, fb, YT);
    k3_part<<<512, 256, 0, stream>>>(tgt, YT, PART);
    k4_red<<<512, 256, 0, stream>>>(PART, out);
}